// Round 9
// baseline (372.250 us; speedup 1.0000x reference)
//
#include <hip/hip_runtime.h>
#include <math.h>
#include <stdint.h>

typedef short short8 __attribute__((ext_vector_type(8)));
typedef short s16x4 __attribute__((ext_vector_type(4)));
typedef float f32x4 __attribute__((ext_vector_type(4)));

constexpr int BB = 2, SS = 2048, EE = 1024, HH = 16, DD = 64, HD = 1024;
constexpr int NROW = BB * SS;  // 4096
constexpr size_t WELEM = (size_t)1024 * 1024;  // elements per weight matrix
constexpr float LN_EPS = 1e-5f;

// split-j schedule: 40 entries per (b,h); entry e covers q-tile ENT_QT[e],
// j-tiles [ENT_C0[e]*8, min(+8, 2*qt+2)). EBASE[qt] = first entry of qt.
__device__ const int ENT_QT[40] = {0,1,2,3, 4,4, 5,5, 6,6, 7,7,
                                   8,8,8, 9,9,9, 10,10,10, 11,11,11,
                                   12,12,12,12, 13,13,13,13, 14,14,14,14, 15,15,15,15};
__device__ const int ENT_C0[40] = {0,0,0,0, 0,1, 0,1, 0,1, 0,1,
                                   0,1,2, 0,1,2, 0,1,2, 0,1,2,
                                   0,1,2,3, 0,1,2,3, 0,1,2,3, 0,1,2,3};
__device__ const int EBASE[16]  = {0,1,2,3,4,6,8,10,12,15,18,21,24,28,32,36};
constexpr int NENT = 40;

#if defined(__has_builtin)
#if __has_builtin(__builtin_amdgcn_exp2f)
#define EXP2F(x) __builtin_amdgcn_exp2f(x)
#endif
#endif
#ifndef EXP2F
#define EXP2F(x) exp2f(x)
#endif

__device__ inline short f2bf(float f) {
    union { float f; uint32_t u; } v; v.f = f;
    uint32_t r = (v.u + 0x7fffu + ((v.u >> 16) & 1u)) >> 16;
    return (short)(uint16_t)r;
}

__device__ inline float bf2f(short s) {
    return __uint_as_float(((uint32_t)(uint16_t)s) << 16);
}

// pack two f32 -> two bf16 (round-half-up) in one dword via v_perm
__device__ inline uint32_t pk2bf(float f0, float f1) {
    uint32_t u0 = __float_as_uint(f0) + 0x8000u;
    uint32_t u1 = __float_as_uint(f1) + 0x8000u;
    return __builtin_amdgcn_perm(u1, u0, 0x07060302u);
}

// truncating pack (no round-add): bias cancels between O-numerator and l-sum
__device__ inline uint32_t pk2bf_t(float f0, float f1) {
    return __builtin_amdgcn_perm(__float_as_uint(f1), __float_as_uint(f0), 0x07060302u);
}

__device__ inline s16x4 pack_bf16x4(f32x4 v) {
    union { uint32_t u[2]; s16x4 s; } r;
    r.u[0] = pk2bf(v[0], v[1]);
    r.u[1] = pk2bf(v[2], v[3]);
    return r.s;
}

#define GLOBAL_TO_LDS16(g, l) \
    __builtin_amdgcn_global_load_lds( \
        (const __attribute__((address_space(1))) void*)(g), \
        (__attribute__((address_space(3))) void*)(l), 16, 0, 0)

// ---------------------------------------------------------------------------
// Merged prep: blocks [0,4096) LayerNorm rows; [4096,8192) weight transpose.
// Block 0 also zeroes the attn completion counters (visible at next kernel).
// ---------------------------------------------------------------------------
__global__ void prep_kernel(const float* __restrict__ x,
                            const float* __restrict__ g,
                            const float* __restrict__ b,
                            short* __restrict__ xn,
                            const float* __restrict__ w0, const float* __restrict__ w1,
                            const float* __restrict__ w2, const float* __restrict__ w3,
                            short* __restrict__ wdst, int* __restrict__ cnt) {
    const int bx = blockIdx.x;
    const int t = threadIdx.x;
    if (bx < NROW) {  // ---- LayerNorm ----
        if (bx == 0) {           // zero 384 completion counters
            cnt[t] = 0;
            if (t < 128) cnt[256 + t] = 0;
        }
        const int row = bx;
        const float* xr = x + (size_t)row * EE;
        short* onr = xn + (size_t)row * EE;
        float4 v = ((const float4*)xr)[t];
        float s  = v.x + v.y + v.z + v.w;
        float ss = v.x * v.x + v.y * v.y + v.z * v.z + v.w * v.w;
        #pragma unroll
        for (int o = 32; o > 0; o >>= 1) {
            s  += __shfl_down(s, o);
            ss += __shfl_down(ss, o);
        }
        __shared__ float sm[4], sm2[4];
        const int wid = t >> 6, lane = t & 63;
        if (lane == 0) { sm[wid] = s; sm2[wid] = ss; }
        __syncthreads();
        float ts  = sm[0] + sm[1] + sm[2] + sm[3];
        float tss = sm2[0] + sm2[1] + sm2[2] + sm2[3];
        float mean = ts * (1.0f / EE);
        float var  = tss * (1.0f / EE) - mean * mean;
        float inv  = rsqrtf(var + LN_EPS);
        float4 gv = ((const float4*)g)[t];
        float4 bv = ((const float4*)b)[t];
        s16x4 st;
        st.x = f2bf((v.x - mean) * inv * gv.x + bv.x);
        st.y = f2bf((v.y - mean) * inv * gv.y + bv.y);
        st.z = f2bf((v.z - mean) * inv * gv.z + bv.z);
        st.w = f2bf((v.w - mean) * inv * gv.w + bv.w);
        ((s16x4*)onr)[t] = st;
    } else {          // ---- weight transpose+convert ----
        const int widx = bx - NROW;          // 0..4095
        const int z = widx >> 10;
        const int rem = widx & 1023;
        const int k0 = (rem >> 5) * 32, p0 = (rem & 31) * 32;
        const float* src = (z == 0) ? w0 : (z == 1) ? w1 : (z == 2) ? w2 : w3;
        short* d = wdst + (size_t)z * WELEM;
        __shared__ float tile[32][33];
        const int tx = t & 31, ty = t >> 5;
        #pragma unroll
        for (int r = ty; r < 32; r += 8)
            tile[r][tx] = src[(size_t)(k0 + r) * 1024 + p0 + tx];
        __syncthreads();
        #pragma unroll
        for (int r = ty; r < 32; r += 8)
            d[(size_t)(p0 + r) * 1024 + k0 + tx] = f2bf(tile[tx][r]);
    }
}

// ---------------------------------------------------------------------------
// MFMA GEMM (m97 structure): 128x128 tile, BK=32, 4 waves, 16B global_load_lds.
// z==2 (V projection) stores TRANSPOSED: outV[col][row] (vt layout [1024][4096]).
// ---------------------------------------------------------------------------
template <bool F32OUT>
__global__ __launch_bounds__(256) void mfma_gemm(
    const short* __restrict__ A,
    const short* __restrict__ BtBase,
    const float* __restrict__ b0, const float* __restrict__ b1,
    const float* __restrict__ b2,
    short* __restrict__ outB, short* __restrict__ outV,
    const float* __restrict__ resid, float* __restrict__ outF) {
    constexpr int K = 1024, N = 1024;
    const int t = threadIdx.x, lane = t & 63, w = t >> 6;
    const int quad = lane >> 4, l16 = lane & 15;
    const int wm = w >> 1, wn = w & 1;
    const int row0 = blockIdx.y * 128, col0 = blockIdx.x * 128;
    const int z = blockIdx.z;
    const short* Bt = BtBase + (size_t)z * WELEM;
    const float* bias = (z == 0) ? b0 : (z == 1) ? b1 : b2;

    __shared__ short As[128 * 32];
    __shared__ short Bs[128 * 32];

    f32x4 acc[4][4];
    #pragma unroll
    for (int i = 0; i < 4; i++)
        #pragma unroll
        for (int j = 0; j < 4; j++) acc[i][j] = (f32x4){0.f, 0.f, 0.f, 0.f};

    const int srow = t >> 2, schunk = t & 3;
    const short* agp = A  + (size_t)(row0 + srow) * K + schunk * 8;
    const short* bgp = Bt + (size_t)(col0 + srow) * K + schunk * 8;

    for (int k0 = 0; k0 < K; k0 += 32) {
        GLOBAL_TO_LDS16(agp + k0,                    As + t * 8);
        GLOBAL_TO_LDS16(agp + (size_t)64 * K + k0,   As + 2048 + t * 8);
        GLOBAL_TO_LDS16(bgp + k0,                    Bs + t * 8);
        GLOBAL_TO_LDS16(bgp + (size_t)64 * K + k0,   Bs + 2048 + t * 8);
        __syncthreads();
        short8 af[4], bf[4];
        #pragma unroll
        for (int mt = 0; mt < 4; mt++)
            af[mt] = *(const short8*)&As[(wm * 64 + mt * 16 + l16) * 32 + quad * 8];
        #pragma unroll
        for (int nt = 0; nt < 4; nt++)
            bf[nt] = *(const short8*)&Bs[(wn * 64 + nt * 16 + l16) * 32 + quad * 8];
        #pragma unroll
        for (int mt = 0; mt < 4; mt++)
            #pragma unroll
            for (int nt = 0; nt < 4; nt++)
                acc[mt][nt] = __builtin_amdgcn_mfma_f32_16x16x32_bf16(
                    af[mt], bf[nt], acc[mt][nt], 0, 0, 0);
        __syncthreads();
    }

    #pragma unroll
    for (int mt = 0; mt < 4; mt++) {
        #pragma unroll
        for (int nt = 0; nt < 4; nt++) {
            const int rbase = row0 + wm * 64 + mt * 16 + quad * 4;
            const int col = col0 + wn * 64 + nt * 16 + l16;
            const float bcol = bias[col];
            if (F32OUT) {
                #pragma unroll
                for (int r = 0; r < 4; r++)
                    outF[(size_t)(rbase + r) * N + col] =
                        acc[mt][nt][r] + bcol +
                        resid[(size_t)(rbase + r) * N + col];
            } else if (z == 2) {
                union { uint32_t u[2]; s16x4 s; } pk;
                pk.u[0] = pk2bf(acc[mt][nt][0] + bcol, acc[mt][nt][1] + bcol);
                pk.u[1] = pk2bf(acc[mt][nt][2] + bcol, acc[mt][nt][3] + bcol);
                *(s16x4*)&outV[(size_t)col * NROW + rbase] = pk.s;
            } else {
                #pragma unroll
                for (int r = 0; r < 4; r++)
                    outB[(size_t)z * NROW * N + (size_t)(rbase + r) * N + col] =
                        f2bf(acc[mt][nt][r] + bcol);
            }
        }
    }
}

// ---------------------------------------------------------------------------
// Split-j MFMA flash attention v5. Changes vs v4:
//  - Q fragments held in REGISTERS (loaded once from global): no Qs LDS,
//    LDS 48->32 KB => 4 blocks/CU; 8 fewer ds_reads per iter
//  - last-arriver in-kernel reduction (device-scope fence + atomic counter)
//    replaces the attn_reduce kernel
// ---------------------------------------------------------------------------
#define ATTN_ITER(JT, DIAG)                                                     \
    {                                                                           \
        const int jt_ = (JT);                                                   \
        if (jt_ + 1 < jt1) {                                                    \
            const size_t ko = (size_t)(jt_ + 1) * 64 * HD;                      \
            const int vo = (jt_ + 1) * 64;                                      \
            const int ob = (buf ^ 1) * 4096;                                    \
            GLOBAL_TO_LDS16(kb0 + ko, Kb + ob + t * 8);                         \
            GLOBAL_TO_LDS16(kb1 + ko, Kb + ob + (t + 256) * 8);                 \
            GLOBAL_TO_LDS16(vb0 + vo, Vb + ob + t * 8);                         \
            GLOBAL_TO_LDS16(vb1 + vo, Vb + ob + (t + 256) * 8);                 \
        }                                                                       \
        const short* Kc = Kb + buf * 4096;                                      \
        const short* Vc = Vb + buf * 4096;                                      \
        f32x4 s[4][2];                                                          \
        _Pragma("unroll")                                                       \
        for (int mj = 0; mj < 4; mj++)                                          \
            _Pragma("unroll")                                                   \
            for (int nt = 0; nt < 2; nt++) s[mj][nt] = (f32x4){0.f,0.f,0.f,0.f};\
        _Pragma("unroll")                                                       \
        for (int ks = 0; ks < 2; ks++) {                                        \
            const int cq = ((ks * 4 + quad) ^ sw) * 8;                          \
            short8 kf[4];                                                       \
            _Pragma("unroll")                                                   \
            for (int mj = 0; mj < 4; mj++)                                      \
                kf[mj] = *(const short8*)&Kc[(mj * 16 + l16) * 64 + cq];        \
            _Pragma("unroll")                                                   \
            for (int mj = 0; mj < 4; mj++)                                      \
                _Pragma("unroll")                                               \
                for (int nt = 0; nt < 2; nt++)                                  \
                    s[mj][nt] = __builtin_amdgcn_mfma_f32_16x16x32_bf16(        \
                        kf[mj], qreg[nt][ks], s[mj][nt], 0, 0, 0);              \
        }                                                                       \
        const int joff = (jt_ - 2 * qt) * 64;                                   \
        _Pragma("unroll")                                                       \
        for (int mj = 0; mj < 4; mj++) {                                        \
            _Pragma("unroll")                                                   \
            for (int nt = 0; nt < 2; nt++) {                                    \
                const int ir = irel + nt * 16;                                  \
                _Pragma("unroll")                                               \
                for (int r = 0; r < 4; r++) {                                   \
                    float p = EXP2F(s[mj][nt][r] * 0.18033688f);                \
                    if (DIAG) {                                                 \
                        const int jrel = joff + mj * 16 + quad * 4 + r;         \
                        if (jrel > ir) p = 0.f;                                 \
                    }                                                           \
                    s[mj][nt][r] = p;                                           \
                }                                                               \
            }                                                                   \
        }                                                                       \
        _Pragma("unroll")                                                       \
        for (int ks2 = 0; ks2 < 4; ks2++) {                                     \
            s16x4 pf[2];                                                        \
            _Pragma("unroll")                                                   \
            for (int nt = 0; nt < 2; nt++) {                                    \
                union { uint32_t u[2]; s16x4 s4; } r_;                          \
                r_.u[0] = pk2bf_t(s[ks2][nt][0], s[ks2][nt][1]);                \
                r_.u[1] = pk2bf_t(s[ks2][nt][2], s[ks2][nt][3]);                \
                pf[nt] = r_.s4;                                                 \
                Lacc[nt] = __builtin_amdgcn_mfma_f32_16x16x16bf16_1k(           \
                    onesf, pf[nt], Lacc[nt], 0, 0, 0);                          \
            }                                                                   \
            _Pragma("unroll")                                                   \
            for (int mtd = 0; mtd < 4; mtd++) {                                 \
                const int cv = (((ks2 * 2 + (quad >> 1)) ^ sw) * 8) + (quad & 1) * 4;\
                s16x4 vf = *(const s16x4*)&Vc[(mtd * 16 + l16) * 64 + cv];      \
                _Pragma("unroll")                                               \
                for (int nt = 0; nt < 2; nt++)                                  \
                    Ot[mtd][nt] = __builtin_amdgcn_mfma_f32_16x16x16bf16_1k(    \
                        vf, pf[nt], Ot[mtd][nt], 0, 0, 0);                      \
            }                                                                   \
        }                                                                       \
        __syncthreads();                                                        \
        buf ^= 1;                                                               \
    }

__global__ __launch_bounds__(256, 4) void attn_split(
    const short* __restrict__ q, const short* __restrict__ kkk,
    const short* __restrict__ vtp,
    short* __restrict__ OpartB, float* __restrict__ lpart,
    short* __restrict__ attno, int* __restrict__ cnt) {
    const int e = NENT - 1 - (int)blockIdx.x;  // heavy entries dispatch first
    const int h = blockIdx.y, b = blockIdx.z;
    const int qt = ENT_QT[e], c0 = ENT_C0[e];
    const int t = threadIdx.x, lane = t & 63, w = t >> 6;
    const int quad = lane >> 4, l16 = lane & 15;
    const int sw = l16 & 7;
    const int i0 = qt * 128;

    __shared__ short Kb[2 * 64 * 64];
    __shared__ short Vb[2 * 64 * 64];
    __shared__ int oldc_s;

    // ---- Q fragments -> registers (one-time global read) ----
    short8 qreg[2][2];   // [nt][ks]: row = w*32+nt*16+l16, d = ks*32+quad*8
    const size_t qoff = ((size_t)(b * SS + i0)) * HD + h * DD;
    const short* qrow = q + qoff + (size_t)(w * 32 + l16) * HD + quad * 8;
    #pragma unroll
    for (int nt = 0; nt < 2; nt++)
        #pragma unroll
        for (int ks = 0; ks < 2; ks++)
            qreg[nt][ks] = *(const short8*)(qrow + nt * 16 * HD + ks * 32);

    // ---- per-thread K/V staging sources ----
    const int r0 = t >> 3,         cs0 = t & 7;
    const int r1 = (t + 256) >> 3, cs1 = (t + 256) & 7;
    const short* kb0 = kkk + ((size_t)b * SS) * HD + h * DD + (size_t)r0 * HD + (cs0 ^ (r0 & 7)) * 8;
    const short* kb1 = kkk + ((size_t)b * SS) * HD + h * DD + (size_t)r1 * HD + (cs1 ^ (r1 & 7)) * 8;
    const short* vb0 = vtp + ((size_t)(h * 64 + r0)) * NROW + b * SS + (cs0 ^ (r0 & 7)) * 8;
    const short* vb1 = vtp + ((size_t)(h * 64 + r1)) * NROW + b * SS + (cs1 ^ (r1 & 7)) * 8;

    f32x4 Ot[4][2];        // O^T accumulators: [d-tile][i-tile]
    f32x4 Lacc[2];         // ones-MFMA row sums; per-lane reg 0 = sum for i
    #pragma unroll
    for (int mtd = 0; mtd < 4; mtd++)
        #pragma unroll
        for (int nt = 0; nt < 2; nt++) Ot[mtd][nt] = (f32x4){0.f, 0.f, 0.f, 0.f};
    Lacc[0] = (f32x4){0.f, 0.f, 0.f, 0.f};
    Lacc[1] = (f32x4){0.f, 0.f, 0.f, 0.f};
    s16x4 onesf;
    onesf[0] = onesf[1] = onesf[2] = onesf[3] = (short)0x3F80;  // bf16 1.0

    const int jt0 = c0 * 8;
    const int jt1 = min(jt0 + 8, 2 * qt + 2);
    const int irel = w * 32 + l16;

    // stage first K/V tile into buf 0
    {
        const size_t ko = (size_t)jt0 * 64 * HD;
        const int vo = jt0 * 64;
        GLOBAL_TO_LDS16(kb0 + ko, Kb + t * 8);
        GLOBAL_TO_LDS16(kb1 + ko, Kb + (t + 256) * 8);
        GLOBAL_TO_LDS16(vb0 + vo, Vb + t * 8);
        GLOBAL_TO_LDS16(vb1 + vo, Vb + (t + 256) * 8);
    }
    __syncthreads();

    int buf = 0;
    const int dmid   = min(jt1, 2 * qt);   // end of no-mask phase
    const int dstart = max(jt0, 2 * qt);   // start of masked phase
    for (int jt = jt0; jt < dmid; ++jt) ATTN_ITER(jt, false)
    for (int jt = dstart; jt < jt1; ++jt) ATTN_ITER(jt, true)

    if (qt < 4) {
        // single chunk: normalize and write attention output directly
        #pragma unroll
        for (int nt = 0; nt < 2; nt++) {
            const float inv = 1.0f / Lacc[nt][0];
            const int i_abs = i0 + w * 32 + nt * 16 + l16;
            const size_t ob = ((size_t)(b * SS + i_abs)) * HD + h * DD;
            #pragma unroll
            for (int mtd = 0; mtd < 4; mtd++) {
                f32x4 val = Ot[mtd][nt];
                union { uint32_t u[2]; s16x4 s4; } pk;
                pk.u[0] = pk2bf(val[0] * inv, val[1] * inv);
                pk.u[1] = pk2bf(val[2] * inv, val[3] * inv);
                *(s16x4*)&attno[ob + mtd * 16 + quad * 4] = pk.s4;
            }
        }
        return;
    }

    // ---- write unnormalized partials ----
    const int slot = (b * HH + h) * NENT + e;
    #pragma unroll
    for (int nt = 0; nt < 2; nt++) {
        const int i_rel = w * 32 + nt * 16 + l16;
        if (quad == 0) lpart[(size_t)slot * 128 + i_rel] = Lacc[nt][0];
        #pragma unroll
        for (int mtd = 0; mtd < 4; mtd++)
            *(s16x4*)&OpartB[(size_t)slot * 8192 + i_rel * 64 + mtd * 16 + quad * 4] =
                pack_bf16x4(Ot[mtd][nt]);
    }
    __syncthreads();

    // ---- last-arriver reduction ----
    const int nch = (qt >> 2) + 1;
    if (t == 0) {
        __threadfence();  // release: partials visible device-wide
        oldc_s = atomicAdd(&cnt[(b * HH + h) * 12 + (qt - 4)], 1);
    }
    __syncthreads();
    if (oldc_s == nch - 1) {
        __threadfence();  // acquire: other chunks' partials visible
        const int slot0 = (b * HH + h) * NENT + EBASE[qt];
        #pragma unroll
        for (int it = 0; it < 8; it++) {
            const int gg = t + it * 256;          // 0..2047
            const int i = gg >> 4, d4 = (gg & 15) * 4;
            f32x4 acc = (f32x4){0.f, 0.f, 0.f, 0.f};
            float l = 0.f;
            for (int c = 0; c < nch; c++) {
                s16x4 pv = *(const s16x4*)&OpartB[(size_t)(slot0 + c) * 8192 + i * 64 + d4];
                acc[0] += bf2f(pv[0]);
                acc[1] += bf2f(pv[1]);
                acc[2] += bf2f(pv[2]);
                acc[3] += bf2f(pv[3]);
                l += lpart[(size_t)(slot0 + c) * 128 + i];
            }
            const float inv = 1.0f / l;
            union { uint32_t u[2]; s16x4 s4; } pk;
            pk.u[0] = pk2bf(acc[0] * inv, acc[1] * inv);
            pk.u[1] = pk2bf(acc[2] * inv, acc[3] * inv);
            *(s16x4*)&attno[((size_t)(b * SS + i0 + i)) * HD + h * DD + d4] = pk.s4;
        }
    }
}

// ---------------------------------------------------------------------------
// Launch
// ---------------------------------------------------------------------------
extern "C" void kernel_launch(void* const* d_in, const int* in_sizes, int n_in,
                              void* d_out, int out_size, void* d_ws, size_t ws_size,
                              hipStream_t stream) {
    const float* x    = (const float*)d_in[0];
    const float* ln_g = (const float*)d_in[1];
    const float* ln_b = (const float*)d_in[2];
    const float* wq   = (const float*)d_in[3];
    const float* bq   = (const float*)d_in[4];
    const float* wk   = (const float*)d_in[5];
    const float* bk   = (const float*)d_in[6];
    const float* wv   = (const float*)d_in[7];
    const float* bv   = (const float*)d_in[8];
    const float* wo   = (const float*)d_in[9];
    const float* bo   = (const float*)d_in[10];
    float* out = (float*)d_out;

    const size_t buf = (size_t)NROW * HD;   // 4,194,304 elements
    short* xn    = (short*)d_ws;            // 8 MB
    short* qb    = xn + buf;                // q + k row-major: 16 MB
    short* vt    = qb + 2 * buf;            // V^T [1024][4096]: 8 MB
    short* attno = vt + buf;                // 8 MB
    short* wt    = attno + buf;             // 4 x 2 MB bf16 weights
    short* OpB   = wt + 4 * WELEM;          // 1280 x 8192 bf16 = 20 MB
    float* lpart = (float*)(OpB + (size_t)BB * HH * NENT * 8192);  // 0.66 MB
    int*   cnt   = (int*)(lpart + (size_t)BB * HH * NENT * 128);   // 384 ints

    prep_kernel<<<2 * NROW, 256, 0, stream>>>(x, ln_g, ln_b, xn,
                                              wq, wk, wv, wo, wt, cnt);

    // fused QKV: z=0 -> q (row-major), z=1 -> k (row-major), z=2 -> vt (transposed)
    mfma_gemm<false><<<dim3(8, 32, 3), 256, 0, stream>>>(
        xn, wt, bq, bk, bv, qb, vt, nullptr, nullptr);

    attn_split<<<dim3(NENT, HH, BB), 256, 0, stream>>>(
        qb, qb + buf, vt, OpB, lpart, attno, cnt);

    mfma_gemm<true><<<dim3(8, 32, 1), 256, 0, stream>>>(
        attno, wt + 3 * WELEM, bo, bo, bo, nullptr, nullptr, x, out);
}

// Round 10
// 206.242 us; speedup vs baseline: 1.8049x; 1.8049x over previous
//
#include <hip/hip_runtime.h>
#include <math.h>
#include <stdint.h>

typedef short short8 __attribute__((ext_vector_type(8)));
typedef short s16x4 __attribute__((ext_vector_type(4)));
typedef float f32x4 __attribute__((ext_vector_type(4)));

constexpr int BB = 2, SS = 2048, EE = 1024, HH = 16, DD = 64, HD = 1024;
constexpr int NROW = BB * SS;  // 4096
constexpr size_t WELEM = (size_t)1024 * 1024;  // elements per weight matrix
constexpr float LN_EPS = 1e-5f;

// split-j schedule: 40 entries per (b,h); entry e covers q-tile ENT_QT[e],
// j-tiles [ENT_C0[e]*8, min(+8, 2*qt+2)). EBASE[qt] = first entry of qt.
__device__ const int ENT_QT[40] = {0,1,2,3, 4,4, 5,5, 6,6, 7,7,
                                   8,8,8, 9,9,9, 10,10,10, 11,11,11,
                                   12,12,12,12, 13,13,13,13, 14,14,14,14, 15,15,15,15};
__device__ const int ENT_C0[40] = {0,0,0,0, 0,1, 0,1, 0,1, 0,1,
                                   0,1,2, 0,1,2, 0,1,2, 0,1,2,
                                   0,1,2,3, 0,1,2,3, 0,1,2,3, 0,1,2,3};
__device__ const int EBASE[16]  = {0,1,2,3,4,6,8,10,12,15,18,21,24,28,32,36};
constexpr int NENT = 40;

#if defined(__has_builtin)
#if __has_builtin(__builtin_amdgcn_exp2f)
#define EXP2F(x) __builtin_amdgcn_exp2f(x)
#endif
#endif
#ifndef EXP2F
#define EXP2F(x) exp2f(x)
#endif

__device__ inline short f2bf(float f) {
    union { float f; uint32_t u; } v; v.f = f;
    uint32_t r = (v.u + 0x7fffu + ((v.u >> 16) & 1u)) >> 16;
    return (short)(uint16_t)r;
}

__device__ inline float bf2f(short s) {
    return __uint_as_float(((uint32_t)(uint16_t)s) << 16);
}

// pack two f32 -> two bf16 (round-half-up) in one dword via v_perm
__device__ inline uint32_t pk2bf(float f0, float f1) {
    uint32_t u0 = __float_as_uint(f0) + 0x8000u;
    uint32_t u1 = __float_as_uint(f1) + 0x8000u;
    return __builtin_amdgcn_perm(u1, u0, 0x07060302u);
}

// truncating pack (no round-add): bias cancels between O-numerator and l-sum
__device__ inline uint32_t pk2bf_t(float f0, float f1) {
    return __builtin_amdgcn_perm(__float_as_uint(f1), __float_as_uint(f0), 0x07060302u);
}

__device__ inline s16x4 pack_bf16x4(f32x4 v) {
    union { uint32_t u[2]; s16x4 s; } r;
    r.u[0] = pk2bf(v[0], v[1]);
    r.u[1] = pk2bf(v[2], v[3]);
    return r.s;
}

#define GLOBAL_TO_LDS16(g, l) \
    __builtin_amdgcn_global_load_lds( \
        (const __attribute__((address_space(1))) void*)(g), \
        (__attribute__((address_space(3))) void*)(l), 16, 0, 0)

// ---------------------------------------------------------------------------
// Merged prep: blocks [0,4096) LayerNorm rows; [4096,8192) weight transpose.
// ---------------------------------------------------------------------------
__global__ void prep_kernel(const float* __restrict__ x,
                            const float* __restrict__ g,
                            const float* __restrict__ b,
                            short* __restrict__ xn,
                            const float* __restrict__ w0, const float* __restrict__ w1,
                            const float* __restrict__ w2, const float* __restrict__ w3,
                            short* __restrict__ wdst) {
    const int bx = blockIdx.x;
    const int t = threadIdx.x;
    if (bx < NROW) {  // ---- LayerNorm ----
        const int row = bx;
        const float* xr = x + (size_t)row * EE;
        short* onr = xn + (size_t)row * EE;
        float4 v = ((const float4*)xr)[t];
        float s  = v.x + v.y + v.z + v.w;
        float ss = v.x * v.x + v.y * v.y + v.z * v.z + v.w * v.w;
        #pragma unroll
        for (int o = 32; o > 0; o >>= 1) {
            s  += __shfl_down(s, o);
            ss += __shfl_down(ss, o);
        }
        __shared__ float sm[4], sm2[4];
        const int wid = t >> 6, lane = t & 63;
        if (lane == 0) { sm[wid] = s; sm2[wid] = ss; }
        __syncthreads();
        float ts  = sm[0] + sm[1] + sm[2] + sm[3];
        float tss = sm2[0] + sm2[1] + sm2[2] + sm2[3];
        float mean = ts * (1.0f / EE);
        float var  = tss * (1.0f / EE) - mean * mean;
        float inv  = rsqrtf(var + LN_EPS);
        float4 gv = ((const float4*)g)[t];
        float4 bv = ((const float4*)b)[t];
        s16x4 st;
        st.x = f2bf((v.x - mean) * inv * gv.x + bv.x);
        st.y = f2bf((v.y - mean) * inv * gv.y + bv.y);
        st.z = f2bf((v.z - mean) * inv * gv.z + bv.z);
        st.w = f2bf((v.w - mean) * inv * gv.w + bv.w);
        ((s16x4*)onr)[t] = st;
    } else {          // ---- weight transpose+convert ----
        const int widx = bx - NROW;          // 0..4095
        const int z = widx >> 10;
        const int rem = widx & 1023;
        const int k0 = (rem >> 5) * 32, p0 = (rem & 31) * 32;
        const float* src = (z == 0) ? w0 : (z == 1) ? w1 : (z == 2) ? w2 : w3;
        short* d = wdst + (size_t)z * WELEM;
        __shared__ float tile[32][33];
        const int tx = t & 31, ty = t >> 5;
        #pragma unroll
        for (int r = ty; r < 32; r += 8)
            tile[r][tx] = src[(size_t)(k0 + r) * 1024 + p0 + tx];
        __syncthreads();
        #pragma unroll
        for (int r = ty; r < 32; r += 8)
            d[(size_t)(p0 + r) * 1024 + k0 + tx] = f2bf(tile[tx][r]);
    }
}

// ---------------------------------------------------------------------------
// MFMA GEMM (m97 structure): 128x128 tile, BK=32, 4 waves, 16B global_load_lds.
// z==2 (V projection) stores TRANSPOSED: outV[col][row] (vt layout [1024][4096]).
// ---------------------------------------------------------------------------
template <bool F32OUT>
__global__ __launch_bounds__(256) void mfma_gemm(
    const short* __restrict__ A,
    const short* __restrict__ BtBase,
    const float* __restrict__ b0, const float* __restrict__ b1,
    const float* __restrict__ b2,
    short* __restrict__ outB, short* __restrict__ outV,
    const float* __restrict__ resid, float* __restrict__ outF) {
    constexpr int K = 1024, N = 1024;
    const int t = threadIdx.x, lane = t & 63, w = t >> 6;
    const int quad = lane >> 4, l16 = lane & 15;
    const int wm = w >> 1, wn = w & 1;
    const int row0 = blockIdx.y * 128, col0 = blockIdx.x * 128;
    const int z = blockIdx.z;
    const short* Bt = BtBase + (size_t)z * WELEM;
    const float* bias = (z == 0) ? b0 : (z == 1) ? b1 : b2;

    __shared__ short As[128 * 32];
    __shared__ short Bs[128 * 32];

    f32x4 acc[4][4];
    #pragma unroll
    for (int i = 0; i < 4; i++)
        #pragma unroll
        for (int j = 0; j < 4; j++) acc[i][j] = (f32x4){0.f, 0.f, 0.f, 0.f};

    const int srow = t >> 2, schunk = t & 3;
    const short* agp = A  + (size_t)(row0 + srow) * K + schunk * 8;
    const short* bgp = Bt + (size_t)(col0 + srow) * K + schunk * 8;

    for (int k0 = 0; k0 < K; k0 += 32) {
        GLOBAL_TO_LDS16(agp + k0,                    As + t * 8);
        GLOBAL_TO_LDS16(agp + (size_t)64 * K + k0,   As + 2048 + t * 8);
        GLOBAL_TO_LDS16(bgp + k0,                    Bs + t * 8);
        GLOBAL_TO_LDS16(bgp + (size_t)64 * K + k0,   Bs + 2048 + t * 8);
        __syncthreads();
        short8 af[4], bf[4];
        #pragma unroll
        for (int mt = 0; mt < 4; mt++)
            af[mt] = *(const short8*)&As[(wm * 64 + mt * 16 + l16) * 32 + quad * 8];
        #pragma unroll
        for (int nt = 0; nt < 4; nt++)
            bf[nt] = *(const short8*)&Bs[(wn * 64 + nt * 16 + l16) * 32 + quad * 8];
        #pragma unroll
        for (int mt = 0; mt < 4; mt++)
            #pragma unroll
            for (int nt = 0; nt < 4; nt++)
                acc[mt][nt] = __builtin_amdgcn_mfma_f32_16x16x32_bf16(
                    af[mt], bf[nt], acc[mt][nt], 0, 0, 0);
        __syncthreads();
    }

    #pragma unroll
    for (int mt = 0; mt < 4; mt++) {
        #pragma unroll
        for (int nt = 0; nt < 4; nt++) {
            const int rbase = row0 + wm * 64 + mt * 16 + quad * 4;
            const int col = col0 + wn * 64 + nt * 16 + l16;
            const float bcol = bias[col];
            if (F32OUT) {
                #pragma unroll
                for (int r = 0; r < 4; r++)
                    outF[(size_t)(rbase + r) * N + col] =
                        acc[mt][nt][r] + bcol +
                        resid[(size_t)(rbase + r) * N + col];
            } else if (z == 2) {
                union { uint32_t u[2]; s16x4 s; } pk;
                pk.u[0] = pk2bf(acc[mt][nt][0] + bcol, acc[mt][nt][1] + bcol);
                pk.u[1] = pk2bf(acc[mt][nt][2] + bcol, acc[mt][nt][3] + bcol);
                *(s16x4*)&outV[(size_t)col * NROW + rbase] = pk.s;
            } else {
                #pragma unroll
                for (int r = 0; r < 4; r++)
                    outB[(size_t)z * NROW * N + (size_t)(rbase + r) * N + col] =
                        f2bf(acc[mt][nt][r] + bcol);
            }
        }
    }
}

// ---------------------------------------------------------------------------
// Split-j MFMA flash attention v6 = v4 structure + Q-in-registers (v5's win).
// NO in-kernel cross-block reduction (v5's device-scope fences caused a TCC
// writeback storm on non-coherent XCD L2s: 42 -> 226 us). Separate reduce.
// ---------------------------------------------------------------------------
#define ATTN_ITER(JT, DIAG)                                                     \
    {                                                                           \
        const int jt_ = (JT);                                                   \
        if (jt_ + 1 < jt1) {                                                    \
            const size_t ko = (size_t)(jt_ + 1) * 64 * HD;                      \
            const int vo = (jt_ + 1) * 64;                                      \
            const int ob = (buf ^ 1) * 4096;                                    \
            GLOBAL_TO_LDS16(kb0 + ko, Kb + ob + t * 8);                         \
            GLOBAL_TO_LDS16(kb1 + ko, Kb + ob + (t + 256) * 8);                 \
            GLOBAL_TO_LDS16(vb0 + vo, Vb + ob + t * 8);                         \
            GLOBAL_TO_LDS16(vb1 + vo, Vb + ob + (t + 256) * 8);                 \
        }                                                                       \
        const short* Kc = Kb + buf * 4096;                                      \
        const short* Vc = Vb + buf * 4096;                                      \
        f32x4 s[4][2];                                                          \
        _Pragma("unroll")                                                       \
        for (int mj = 0; mj < 4; mj++)                                          \
            _Pragma("unroll")                                                   \
            for (int nt = 0; nt < 2; nt++) s[mj][nt] = (f32x4){0.f,0.f,0.f,0.f};\
        _Pragma("unroll")                                                       \
        for (int ks = 0; ks < 2; ks++) {                                        \
            const int cq = ((ks * 4 + quad) ^ sw) * 8;                          \
            short8 kf[4];                                                       \
            _Pragma("unroll")                                                   \
            for (int mj = 0; mj < 4; mj++)                                      \
                kf[mj] = *(const short8*)&Kc[(mj * 16 + l16) * 64 + cq];        \
            _Pragma("unroll")                                                   \
            for (int mj = 0; mj < 4; mj++)                                      \
                _Pragma("unroll")                                               \
                for (int nt = 0; nt < 2; nt++)                                  \
                    s[mj][nt] = __builtin_amdgcn_mfma_f32_16x16x32_bf16(        \
                        kf[mj], qreg[nt][ks], s[mj][nt], 0, 0, 0);              \
        }                                                                       \
        const int joff = (jt_ - 2 * qt) * 64;                                   \
        _Pragma("unroll")                                                       \
        for (int mj = 0; mj < 4; mj++) {                                        \
            _Pragma("unroll")                                                   \
            for (int nt = 0; nt < 2; nt++) {                                    \
                const int ir = irel + nt * 16;                                  \
                _Pragma("unroll")                                               \
                for (int r = 0; r < 4; r++) {                                   \
                    float p = EXP2F(s[mj][nt][r] * 0.18033688f);                \
                    if (DIAG) {                                                 \
                        const int jrel = joff + mj * 16 + quad * 4 + r;         \
                        if (jrel > ir) p = 0.f;                                 \
                    }                                                           \
                    s[mj][nt][r] = p;                                           \
                }                                                               \
            }                                                                   \
        }                                                                       \
        _Pragma("unroll")                                                       \
        for (int ks2 = 0; ks2 < 4; ks2++) {                                     \
            s16x4 pf[2];                                                        \
            _Pragma("unroll")                                                   \
            for (int nt = 0; nt < 2; nt++) {                                    \
                union { uint32_t u[2]; s16x4 s4; } r_;                          \
                r_.u[0] = pk2bf_t(s[ks2][nt][0], s[ks2][nt][1]);                \
                r_.u[1] = pk2bf_t(s[ks2][nt][2], s[ks2][nt][3]);                \
                pf[nt] = r_.s4;                                                 \
                Lacc[nt] = __builtin_amdgcn_mfma_f32_16x16x16bf16_1k(           \
                    onesf, pf[nt], Lacc[nt], 0, 0, 0);                          \
            }                                                                   \
            _Pragma("unroll")                                                   \
            for (int mtd = 0; mtd < 4; mtd++) {                                 \
                const int cv = (((ks2 * 2 + (quad >> 1)) ^ sw) * 8) + (quad & 1) * 4;\
                s16x4 vf = *(const s16x4*)&Vc[(mtd * 16 + l16) * 64 + cv];      \
                _Pragma("unroll")                                               \
                for (int nt = 0; nt < 2; nt++)                                  \
                    Ot[mtd][nt] = __builtin_amdgcn_mfma_f32_16x16x16bf16_1k(    \
                        vf, pf[nt], Ot[mtd][nt], 0, 0, 0);                      \
            }                                                                   \
        }                                                                       \
        __syncthreads();                                                        \
        buf ^= 1;                                                               \
    }

__global__ __launch_bounds__(256, 4) void attn_split(
    const short* __restrict__ q, const short* __restrict__ kkk,
    const short* __restrict__ vtp,
    short* __restrict__ OpartB, float* __restrict__ lpart,
    short* __restrict__ attno) {
    const int e = NENT - 1 - (int)blockIdx.x;  // heavy entries dispatch first
    const int h = blockIdx.y, b = blockIdx.z;
    const int qt = ENT_QT[e], c0 = ENT_C0[e];
    const int t = threadIdx.x, lane = t & 63, w = t >> 6;
    const int quad = lane >> 4, l16 = lane & 15;
    const int sw = l16 & 7;
    const int i0 = qt * 128;

    __shared__ short Kb[2 * 64 * 64];
    __shared__ short Vb[2 * 64 * 64];

    // ---- Q fragments -> registers (one-time global read) ----
    short8 qreg[2][2];   // [nt][ks]: row = w*32+nt*16+l16, d = ks*32+quad*8
    const size_t qoff = ((size_t)(b * SS + i0)) * HD + h * DD;
    const short* qrow = q + qoff + (size_t)(w * 32 + l16) * HD + quad * 8;
    #pragma unroll
    for (int nt = 0; nt < 2; nt++)
        #pragma unroll
        for (int ks = 0; ks < 2; ks++)
            qreg[nt][ks] = *(const short8*)(qrow + nt * 16 * HD + ks * 32);

    // ---- per-thread K/V staging sources ----
    const int r0 = t >> 3,         cs0 = t & 7;
    const int r1 = (t + 256) >> 3, cs1 = (t + 256) & 7;
    const short* kb0 = kkk + ((size_t)b * SS) * HD + h * DD + (size_t)r0 * HD + (cs0 ^ (r0 & 7)) * 8;
    const short* kb1 = kkk + ((size_t)b * SS) * HD + h * DD + (size_t)r1 * HD + (cs1 ^ (r1 & 7)) * 8;
    const short* vb0 = vtp + ((size_t)(h * 64 + r0)) * NROW + b * SS + (cs0 ^ (r0 & 7)) * 8;
    const short* vb1 = vtp + ((size_t)(h * 64 + r1)) * NROW + b * SS + (cs1 ^ (r1 & 7)) * 8;

    f32x4 Ot[4][2];        // O^T accumulators: [d-tile][i-tile]
    f32x4 Lacc[2];         // ones-MFMA row sums; per-lane reg 0 = sum for i
    #pragma unroll
    for (int mtd = 0; mtd < 4; mtd++)
        #pragma unroll
        for (int nt = 0; nt < 2; nt++) Ot[mtd][nt] = (f32x4){0.f, 0.f, 0.f, 0.f};
    Lacc[0] = (f32x4){0.f, 0.f, 0.f, 0.f};
    Lacc[1] = (f32x4){0.f, 0.f, 0.f, 0.f};
    s16x4 onesf;
    onesf[0] = onesf[1] = onesf[2] = onesf[3] = (short)0x3F80;  // bf16 1.0

    const int jt0 = c0 * 8;
    const int jt1 = min(jt0 + 8, 2 * qt + 2);
    const int irel = w * 32 + l16;

    // stage first K/V tile into buf 0
    {
        const size_t ko = (size_t)jt0 * 64 * HD;
        const int vo = jt0 * 64;
        GLOBAL_TO_LDS16(kb0 + ko, Kb + t * 8);
        GLOBAL_TO_LDS16(kb1 + ko, Kb + (t + 256) * 8);
        GLOBAL_TO_LDS16(vb0 + vo, Vb + t * 8);
        GLOBAL_TO_LDS16(vb1 + vo, Vb + (t + 256) * 8);
    }
    __syncthreads();

    int buf = 0;
    const int dmid   = min(jt1, 2 * qt);   // end of no-mask phase
    const int dstart = max(jt0, 2 * qt);   // start of masked phase
    for (int jt = jt0; jt < dmid; ++jt) ATTN_ITER(jt, false)
    for (int jt = dstart; jt < jt1; ++jt) ATTN_ITER(jt, true)

    if (qt < 4) {
        // single chunk: normalize and write attention output directly
        #pragma unroll
        for (int nt = 0; nt < 2; nt++) {
            const float inv = 1.0f / Lacc[nt][0];
            const int i_abs = i0 + w * 32 + nt * 16 + l16;
            const size_t ob = ((size_t)(b * SS + i_abs)) * HD + h * DD;
            #pragma unroll
            for (int mtd = 0; mtd < 4; mtd++) {
                f32x4 val = Ot[mtd][nt];
                union { uint32_t u[2]; s16x4 s4; } pk;
                pk.u[0] = pk2bf(val[0] * inv, val[1] * inv);
                pk.u[1] = pk2bf(val[2] * inv, val[3] * inv);
                *(s16x4*)&attno[ob + mtd * 16 + quad * 4] = pk.s4;
            }
        }
        return;
    }

    // ---- write unnormalized partials (combined by attn_reduce) ----
    const int slot = (b * HH + h) * NENT + e;
    #pragma unroll
    for (int nt = 0; nt < 2; nt++) {
        const int i_rel = w * 32 + nt * 16 + l16;
        if (quad == 0) lpart[(size_t)slot * 128 + i_rel] = Lacc[nt][0];
        #pragma unroll
        for (int mtd = 0; mtd < 4; mtd++)
            *(s16x4*)&OpartB[(size_t)slot * 8192 + i_rel * 64 + mtd * 16 + quad * 4] =
                pack_bf16x4(Ot[mtd][nt]);
    }
}

// ---------------------------------------------------------------------------
// Combine partials for qt >= 4 (multi-chunk q-tiles only).
// ---------------------------------------------------------------------------
__global__ __launch_bounds__(256) void attn_reduce(
    const short* __restrict__ OpartB, const float* __restrict__ lpart,
    short* __restrict__ attno) {
    const int qt = 4 + blockIdx.x, h = blockIdx.y, b = blockIdx.z;
    const int t = threadIdx.x;
    const int nch = (qt >> 2) + 1;
    const int slot0 = (b * HH + h) * NENT + EBASE[qt];
    const int i0 = qt * 128;
    #pragma unroll
    for (int it = 0; it < 8; it++) {
        const int g = t + it * 256;           // 0..2047
        const int i = g >> 4, d4 = (g & 15) * 4;
        f32x4 acc = (f32x4){0.f, 0.f, 0.f, 0.f};
        float l = 0.f;
        for (int c = 0; c < nch; c++) {
            s16x4 pv = *(const s16x4*)&OpartB[(size_t)(slot0 + c) * 8192 + i * 64 + d4];
            acc[0] += bf2f(pv[0]);
            acc[1] += bf2f(pv[1]);
            acc[2] += bf2f(pv[2]);
            acc[3] += bf2f(pv[3]);
            l += lpart[(size_t)(slot0 + c) * 128 + i];
        }
        const float inv = 1.0f / l;
        union { uint32_t u[2]; s16x4 s; } pk;
        pk.u[0] = pk2bf(acc[0] * inv, acc[1] * inv);
        pk.u[1] = pk2bf(acc[2] * inv, acc[3] * inv);
        *(s16x4*)&attno[((size_t)(b * SS + i0 + i)) * HD + h * DD + d4] = pk.s;
    }
}

// ---------------------------------------------------------------------------
// Launch
// ---------------------------------------------------------------------------
extern "C" void kernel_launch(void* const* d_in, const int* in_sizes, int n_in,
                              void* d_out, int out_size, void* d_ws, size_t ws_size,
                              hipStream_t stream) {
    const float* x    = (const float*)d_in[0];
    const float* ln_g = (const float*)d_in[1];
    const float* ln_b = (const float*)d_in[2];
    const float* wq   = (const float*)d_in[3];
    const float* bq   = (const float*)d_in[4];
    const float* wk   = (const float*)d_in[5];
    const float* bk   = (const float*)d_in[6];
    const float* wv   = (const float*)d_in[7];
    const float* bv   = (const float*)d_in[8];
    const float* wo   = (const float*)d_in[9];
    const float* bo   = (const float*)d_in[10];
    float* out = (float*)d_out;

    const size_t buf = (size_t)NROW * HD;   // 4,194,304 elements
    short* xn    = (short*)d_ws;            // 8 MB
    short* qb    = xn + buf;                // q + k row-major: 16 MB
    short* vt    = qb + 2 * buf;            // V^T [1024][4096]: 8 MB
    short* attno = vt + buf;                // 8 MB
    short* wt    = attno + buf;             // 4 x 2 MB bf16 weights
    short* OpB   = wt + 4 * WELEM;          // 1280 x 8192 bf16 = 20 MB
    float* lpart = (float*)(OpB + (size_t)BB * HH * NENT * 8192);  // 0.66 MB

    prep_kernel<<<2 * NROW, 256, 0, stream>>>(x, ln_g, ln_b, xn,
                                              wq, wk, wv, wo, wt);

    // fused QKV: z=0 -> q (row-major), z=1 -> k (row-major), z=2 -> vt (transposed)
    mfma_gemm<false><<<dim3(8, 32, 3), 256, 0, stream>>>(
        xn, wt, bq, bk, bv, qb, vt, nullptr, nullptr);

    attn_split<<<dim3(NENT, HH, BB), 256, 0, stream>>>(
        qb, qb + buf, vt, OpB, lpart, attno);
    attn_reduce<<<dim3(12, HH, BB), 256, 0, stream>>>(OpB, lpart, attno);

    mfma_gemm<true><<<dim3(8, 32, 1), 256, 0, stream>>>(
        attno, wt + 3 * WELEM, bo, bo, bo, nullptr, nullptr, x, out);
}

// Round 11
// 202.481 us; speedup vs baseline: 1.8384x; 1.0186x over previous
//
#include <hip/hip_runtime.h>
#include <math.h>
#include <stdint.h>

typedef short short8 __attribute__((ext_vector_type(8)));
typedef short s16x4 __attribute__((ext_vector_type(4)));
typedef float f32x4 __attribute__((ext_vector_type(4)));

constexpr int BB = 2, SS = 2048, EE = 1024, HH = 16, DD = 64, HD = 1024;
constexpr int NROW = BB * SS;  // 4096
constexpr size_t WELEM = (size_t)1024 * 1024;  // elements per weight matrix
constexpr float LN_EPS = 1e-5f;

// split-j schedule: 40 entries per (b,h); entry e covers q-tile ENT_QT[e],
// j-tiles [ENT_C0[e]*8, min(+8, 2*qt+2)). EBASE[qt] = first entry of qt.
__device__ const int ENT_QT[40] = {0,1,2,3, 4,4, 5,5, 6,6, 7,7,
                                   8,8,8, 9,9,9, 10,10,10, 11,11,11,
                                   12,12,12,12, 13,13,13,13, 14,14,14,14, 15,15,15,15};
__device__ const int ENT_C0[40] = {0,0,0,0, 0,1, 0,1, 0,1, 0,1,
                                   0,1,2, 0,1,2, 0,1,2, 0,1,2,
                                   0,1,2,3, 0,1,2,3, 0,1,2,3, 0,1,2,3};
__device__ const int EBASE[16]  = {0,1,2,3,4,6,8,10,12,15,18,21,24,28,32,36};
constexpr int NENT = 40;

#if defined(__has_builtin)
#if __has_builtin(__builtin_amdgcn_exp2f)
#define EXP2F(x) __builtin_amdgcn_exp2f(x)
#endif
#endif
#ifndef EXP2F
#define EXP2F(x) exp2f(x)
#endif

__device__ inline short f2bf(float f) {
    union { float f; uint32_t u; } v; v.f = f;
    uint32_t r = (v.u + 0x7fffu + ((v.u >> 16) & 1u)) >> 16;
    return (short)(uint16_t)r;
}

__device__ inline float bf2f(short s) {
    return __uint_as_float(((uint32_t)(uint16_t)s) << 16);
}

// pack two f32 -> two bf16 (round-half-up) in one dword via v_perm
__device__ inline uint32_t pk2bf(float f0, float f1) {
    uint32_t u0 = __float_as_uint(f0) + 0x8000u;
    uint32_t u1 = __float_as_uint(f1) + 0x8000u;
    return __builtin_amdgcn_perm(u1, u0, 0x07060302u);
}

// truncating pack (no round-add): bias cancels between O-numerator and l-sum
__device__ inline uint32_t pk2bf_t(float f0, float f1) {
    return __builtin_amdgcn_perm(__float_as_uint(f1), __float_as_uint(f0), 0x07060302u);
}

__device__ inline s16x4 pack_bf16x4(f32x4 v) {
    union { uint32_t u[2]; s16x4 s; } r;
    r.u[0] = pk2bf(v[0], v[1]);
    r.u[1] = pk2bf(v[2], v[3]);
    return r.s;
}

#define GLOBAL_TO_LDS16(g, l) \
    __builtin_amdgcn_global_load_lds( \
        (const __attribute__((address_space(1))) void*)(g), \
        (__attribute__((address_space(3))) void*)(l), 16, 0, 0)

// ---------------------------------------------------------------------------
// Merged prep: blocks [0,4096) LayerNorm rows; [4096,8192) weight transpose.
// ---------------------------------------------------------------------------
__global__ void prep_kernel(const float* __restrict__ x,
                            const float* __restrict__ g,
                            const float* __restrict__ b,
                            short* __restrict__ xn,
                            const float* __restrict__ w0, const float* __restrict__ w1,
                            const float* __restrict__ w2, const float* __restrict__ w3,
                            short* __restrict__ wdst) {
    const int bx = blockIdx.x;
    const int t = threadIdx.x;
    if (bx < NROW) {  // ---- LayerNorm ----
        const int row = bx;
        const float* xr = x + (size_t)row * EE;
        short* onr = xn + (size_t)row * EE;
        float4 v = ((const float4*)xr)[t];
        float s  = v.x + v.y + v.z + v.w;
        float ss = v.x * v.x + v.y * v.y + v.z * v.z + v.w * v.w;
        #pragma unroll
        for (int o = 32; o > 0; o >>= 1) {
            s  += __shfl_down(s, o);
            ss += __shfl_down(ss, o);
        }
        __shared__ float sm[4], sm2[4];
        const int wid = t >> 6, lane = t & 63;
        if (lane == 0) { sm[wid] = s; sm2[wid] = ss; }
        __syncthreads();
        float ts  = sm[0] + sm[1] + sm[2] + sm[3];
        float tss = sm2[0] + sm2[1] + sm2[2] + sm2[3];
        float mean = ts * (1.0f / EE);
        float var  = tss * (1.0f / EE) - mean * mean;
        float inv  = rsqrtf(var + LN_EPS);
        float4 gv = ((const float4*)g)[t];
        float4 bv = ((const float4*)b)[t];
        s16x4 st;
        st.x = f2bf((v.x - mean) * inv * gv.x + bv.x);
        st.y = f2bf((v.y - mean) * inv * gv.y + bv.y);
        st.z = f2bf((v.z - mean) * inv * gv.z + bv.z);
        st.w = f2bf((v.w - mean) * inv * gv.w + bv.w);
        ((s16x4*)onr)[t] = st;
    } else {          // ---- weight transpose+convert ----
        const int widx = bx - NROW;          // 0..4095
        const int z = widx >> 10;
        const int rem = widx & 1023;
        const int k0 = (rem >> 5) * 32, p0 = (rem & 31) * 32;
        const float* src = (z == 0) ? w0 : (z == 1) ? w1 : (z == 2) ? w2 : w3;
        short* d = wdst + (size_t)z * WELEM;
        __shared__ float tile[32][33];
        const int tx = t & 31, ty = t >> 5;
        #pragma unroll
        for (int r = ty; r < 32; r += 8)
            tile[r][tx] = src[(size_t)(k0 + r) * 1024 + p0 + tx];
        __syncthreads();
        #pragma unroll
        for (int r = ty; r < 32; r += 8)
            d[(size_t)(p0 + r) * 1024 + k0 + tx] = f2bf(tile[tx][r]);
    }
}

// ---------------------------------------------------------------------------
// MFMA GEMM v2: 128(M)x64(N) tile, BK=64, 256 thr = 4 waves (each 32x64),
// XOR-swizzled global_load_lds staging (swizzle on SOURCE k-chunk, linear LDS
// dest) -> conflict-free ds_read_b128 fragment reads. 16 k-iters, 16 MFMA +
// 6 staging loads per wave-iter. Grid: (M/128, N/64, z).
// z==2 (V projection) stores TRANSPOSED: outV[col][row] (vt [1024][4096]).
// ---------------------------------------------------------------------------
template <bool F32OUT>
__global__ __launch_bounds__(256, 4) void mfma_gemm(
    const short* __restrict__ A,
    const short* __restrict__ BtBase,
    const float* __restrict__ b0, const float* __restrict__ b1,
    const float* __restrict__ b2,
    short* __restrict__ outB, short* __restrict__ outV,
    const float* __restrict__ resid, float* __restrict__ outF) {
    constexpr int K = 1024, N = 1024;
    const int t = threadIdx.x, lane = t & 63, w = t >> 6;
    const int quad = lane >> 4, l16 = lane & 15;
    const int row0 = blockIdx.x * 128, col0 = blockIdx.y * 64;
    const int z = blockIdx.z;
    const short* Bt = BtBase + (size_t)z * WELEM;
    const float* bias = (z == 0) ? b0 : (z == 1) ? b1 : b2;

    __shared__ short As[128 * 64];   // 16 KB
    __shared__ short Bs[64 * 64];    // 8 KB

    f32x4 acc[2][4];
    #pragma unroll
    for (int i = 0; i < 2; i++)
        #pragma unroll
        for (int j = 0; j < 4; j++) acc[i][j] = (f32x4){0.f, 0.f, 0.f, 0.f};

    // staging sources: thread t covers chunk-ids {t, t+256, t+512, t+768} of A
    // (row = cid>>3, chunk c = cid&7) and {t, t+256} of B. Source k-offset is
    // XOR-swizzled so LDS slot cs of row r holds global chunk cs^(r&7).
    const int sr = t >> 3, sc = t & 7;
    const int swc = (sc ^ (sr & 7)) * 8;   // sr&7 invariant under +32
    const short* ap0 = A + (size_t)(row0 + sr) * K + swc;
    const short* ap1 = ap0 + (size_t)32 * K;
    const short* ap2 = ap0 + (size_t)64 * K;
    const short* ap3 = ap0 + (size_t)96 * K;
    const short* bp0 = Bt + (size_t)(col0 + sr) * K + swc;
    const short* bp1 = bp0 + (size_t)32 * K;

    for (int k0 = 0; k0 < K; k0 += 64) {
        GLOBAL_TO_LDS16(ap0 + k0, As + t * 8);
        GLOBAL_TO_LDS16(ap1 + k0, As + (t + 256) * 8);
        GLOBAL_TO_LDS16(ap2 + k0, As + (t + 512) * 8);
        GLOBAL_TO_LDS16(ap3 + k0, As + (t + 768) * 8);
        GLOBAL_TO_LDS16(bp0 + k0, Bs + t * 8);
        GLOBAL_TO_LDS16(bp1 + k0, Bs + (t + 256) * 8);
        __syncthreads();
        #pragma unroll
        for (int ks = 0; ks < 2; ks++) {
            const int ca = ((ks * 4 + quad) ^ (l16 & 7)) * 8;  // swizzled slot
            short8 af[2], bf[4];
            #pragma unroll
            for (int mt = 0; mt < 2; mt++)
                af[mt] = *(const short8*)&As[(w * 32 + mt * 16 + l16) * 64 + ca];
            #pragma unroll
            for (int nt = 0; nt < 4; nt++)
                bf[nt] = *(const short8*)&Bs[(nt * 16 + l16) * 64 + ca];
            #pragma unroll
            for (int mt = 0; mt < 2; mt++)
                #pragma unroll
                for (int nt = 0; nt < 4; nt++)
                    acc[mt][nt] = __builtin_amdgcn_mfma_f32_16x16x32_bf16(
                        af[mt], bf[nt], acc[mt][nt], 0, 0, 0);
        }
        __syncthreads();
    }

    #pragma unroll
    for (int mt = 0; mt < 2; mt++) {
        #pragma unroll
        for (int nt = 0; nt < 4; nt++) {
            const int rbase = row0 + w * 32 + mt * 16 + quad * 4;
            const int col = col0 + nt * 16 + l16;
            const float bcol = bias[col];
            if (F32OUT) {
                #pragma unroll
                for (int r = 0; r < 4; r++)
                    outF[(size_t)(rbase + r) * N + col] =
                        acc[mt][nt][r] + bcol +
                        resid[(size_t)(rbase + r) * N + col];
            } else if (z == 2) {
                union { uint32_t u[2]; s16x4 s; } pk;
                pk.u[0] = pk2bf(acc[mt][nt][0] + bcol, acc[mt][nt][1] + bcol);
                pk.u[1] = pk2bf(acc[mt][nt][2] + bcol, acc[mt][nt][3] + bcol);
                *(s16x4*)&outV[(size_t)col * NROW + rbase] = pk.s;
            } else {
                #pragma unroll
                for (int r = 0; r < 4; r++)
                    outB[(size_t)z * NROW * N + (size_t)(rbase + r) * N + col] =
                        f2bf(acc[mt][nt][r] + bcol);
            }
        }
    }
}

// ---------------------------------------------------------------------------
// Split-j MFMA flash attention (unchanged from round 10, the passing version).
// ---------------------------------------------------------------------------
#define ATTN_ITER(JT, DIAG)                                                     \
    {                                                                           \
        const int jt_ = (JT);                                                   \
        if (jt_ + 1 < jt1) {                                                    \
            const size_t ko = (size_t)(jt_ + 1) * 64 * HD;                      \
            const int vo = (jt_ + 1) * 64;                                      \
            const int ob = (buf ^ 1) * 4096;                                    \
            GLOBAL_TO_LDS16(kb0 + ko, Kb + ob + t * 8);                         \
            GLOBAL_TO_LDS16(kb1 + ko, Kb + ob + (t + 256) * 8);                 \
            GLOBAL_TO_LDS16(vb0 + vo, Vb + ob + t * 8);                         \
            GLOBAL_TO_LDS16(vb1 + vo, Vb + ob + (t + 256) * 8);                 \
        }                                                                       \
        const short* Kc = Kb + buf * 4096;                                      \
        const short* Vc = Vb + buf * 4096;                                      \
        f32x4 s[4][2];                                                          \
        _Pragma("unroll")                                                       \
        for (int mj = 0; mj < 4; mj++)                                          \
            _Pragma("unroll")                                                   \
            for (int nt = 0; nt < 2; nt++) s[mj][nt] = (f32x4){0.f,0.f,0.f,0.f};\
        _Pragma("unroll")                                                       \
        for (int ks = 0; ks < 2; ks++) {                                        \
            const int cq = ((ks * 4 + quad) ^ sw) * 8;                          \
            short8 kf[4];                                                       \
            _Pragma("unroll")                                                   \
            for (int mj = 0; mj < 4; mj++)                                      \
                kf[mj] = *(const short8*)&Kc[(mj * 16 + l16) * 64 + cq];        \
            _Pragma("unroll")                                                   \
            for (int mj = 0; mj < 4; mj++)                                      \
                _Pragma("unroll")                                               \
                for (int nt = 0; nt < 2; nt++)                                  \
                    s[mj][nt] = __builtin_amdgcn_mfma_f32_16x16x32_bf16(        \
                        kf[mj], qreg[nt][ks], s[mj][nt], 0, 0, 0);              \
        }                                                                       \
        const int joff = (jt_ - 2 * qt) * 64;                                   \
        _Pragma("unroll")                                                       \
        for (int mj = 0; mj < 4; mj++) {                                        \
            _Pragma("unroll")                                                   \
            for (int nt = 0; nt < 2; nt++) {                                    \
                const int ir = irel + nt * 16;                                  \
                _Pragma("unroll")                                               \
                for (int r = 0; r < 4; r++) {                                   \
                    float p = EXP2F(s[mj][nt][r] * 0.18033688f);                \
                    if (DIAG) {                                                 \
                        const int jrel = joff + mj * 16 + quad * 4 + r;         \
                        if (jrel > ir) p = 0.f;                                 \
                    }                                                           \
                    s[mj][nt][r] = p;                                           \
                }                                                               \
            }                                                                   \
        }                                                                       \
        _Pragma("unroll")                                                       \
        for (int ks2 = 0; ks2 < 4; ks2++) {                                     \
            s16x4 pf[2];                                                        \
            _Pragma("unroll")                                                   \
            for (int nt = 0; nt < 2; nt++) {                                    \
                union { uint32_t u[2]; s16x4 s4; } r_;                          \
                r_.u[0] = pk2bf_t(s[ks2][nt][0], s[ks2][nt][1]);                \
                r_.u[1] = pk2bf_t(s[ks2][nt][2], s[ks2][nt][3]);                \
                pf[nt] = r_.s4;                                                 \
                Lacc[nt] = __builtin_amdgcn_mfma_f32_16x16x16bf16_1k(           \
                    onesf, pf[nt], Lacc[nt], 0, 0, 0);                          \
            }                                                                   \
            _Pragma("unroll")                                                   \
            for (int mtd = 0; mtd < 4; mtd++) {                                 \
                const int cv = (((ks2 * 2 + (quad >> 1)) ^ sw) * 8) + (quad & 1) * 4;\
                s16x4 vf = *(const s16x4*)&Vc[(mtd * 16 + l16) * 64 + cv];      \
                _Pragma("unroll")                                               \
                for (int nt = 0; nt < 2; nt++)                                  \
                    Ot[mtd][nt] = __builtin_amdgcn_mfma_f32_16x16x16bf16_1k(    \
                        vf, pf[nt], Ot[mtd][nt], 0, 0, 0);                      \
            }                                                                   \
        }                                                                       \
        __syncthreads();                                                        \
        buf ^= 1;                                                               \
    }

__global__ __launch_bounds__(256, 4) void attn_split(
    const short* __restrict__ q, const short* __restrict__ kkk,
    const short* __restrict__ vtp,
    short* __restrict__ OpartB, float* __restrict__ lpart,
    short* __restrict__ attno) {
    const int e = NENT - 1 - (int)blockIdx.x;  // heavy entries dispatch first
    const int h = blockIdx.y, b = blockIdx.z;
    const int qt = ENT_QT[e], c0 = ENT_C0[e];
    const int t = threadIdx.x, lane = t & 63, w = t >> 6;
    const int quad = lane >> 4, l16 = lane & 15;
    const int sw = l16 & 7;
    const int i0 = qt * 128;

    __shared__ short Kb[2 * 64 * 64];
    __shared__ short Vb[2 * 64 * 64];

    // ---- Q fragments -> registers (one-time global read) ----
    short8 qreg[2][2];   // [nt][ks]: row = w*32+nt*16+l16, d = ks*32+quad*8
    const size_t qoff = ((size_t)(b * SS + i0)) * HD + h * DD;
    const short* qrow = q + qoff + (size_t)(w * 32 + l16) * HD + quad * 8;
    #pragma unroll
    for (int nt = 0; nt < 2; nt++)
        #pragma unroll
        for (int ks = 0; ks < 2; ks++)
            qreg[nt][ks] = *(const short8*)(qrow + nt * 16 * HD + ks * 32);

    // ---- per-thread K/V staging sources ----
    const int r0 = t >> 3,         cs0 = t & 7;
    const int r1 = (t + 256) >> 3, cs1 = (t + 256) & 7;
    const short* kb0 = kkk + ((size_t)b * SS) * HD + h * DD + (size_t)r0 * HD + (cs0 ^ (r0 & 7)) * 8;
    const short* kb1 = kkk + ((size_t)b * SS) * HD + h * DD + (size_t)r1 * HD + (cs1 ^ (r1 & 7)) * 8;
    const short* vb0 = vtp + ((size_t)(h * 64 + r0)) * NROW + b * SS + (cs0 ^ (r0 & 7)) * 8;
    const short* vb1 = vtp + ((size_t)(h * 64 + r1)) * NROW + b * SS + (cs1 ^ (r1 & 7)) * 8;

    f32x4 Ot[4][2];        // O^T accumulators: [d-tile][i-tile]
    f32x4 Lacc[2];         // ones-MFMA row sums; per-lane reg 0 = sum for i
    #pragma unroll
    for (int mtd = 0; mtd < 4; mtd++)
        #pragma unroll
        for (int nt = 0; nt < 2; nt++) Ot[mtd][nt] = (f32x4){0.f, 0.f, 0.f, 0.f};
    Lacc[0] = (f32x4){0.f, 0.f, 0.f, 0.f};
    Lacc[1] = (f32x4){0.f, 0.f, 0.f, 0.f};
    s16x4 onesf;
    onesf[0] = onesf[1] = onesf[2] = onesf[3] = (short)0x3F80;  // bf16 1.0

    const int jt0 = c0 * 8;
    const int jt1 = min(jt0 + 8, 2 * qt + 2);
    const int irel = w * 32 + l16;

    // stage first K/V tile into buf 0
    {
        const size_t ko = (size_t)jt0 * 64 * HD;
        const int vo = jt0 * 64;
        GLOBAL_TO_LDS16(kb0 + ko, Kb + t * 8);
        GLOBAL_TO_LDS16(kb1 + ko, Kb + (t + 256) * 8);
        GLOBAL_TO_LDS16(vb0 + vo, Vb + t * 8);
        GLOBAL_TO_LDS16(vb1 + vo, Vb + (t + 256) * 8);
    }
    __syncthreads();

    int buf = 0;
    const int dmid   = min(jt1, 2 * qt);   // end of no-mask phase
    const int dstart = max(jt0, 2 * qt);   // start of masked phase
    for (int jt = jt0; jt < dmid; ++jt) ATTN_ITER(jt, false)
    for (int jt = dstart; jt < jt1; ++jt) ATTN_ITER(jt, true)

    if (qt < 4) {
        // single chunk: normalize and write attention output directly
        #pragma unroll
        for (int nt = 0; nt < 2; nt++) {
            const float inv = 1.0f / Lacc[nt][0];
            const int i_abs = i0 + w * 32 + nt * 16 + l16;
            const size_t ob = ((size_t)(b * SS + i_abs)) * HD + h * DD;
            #pragma unroll
            for (int mtd = 0; mtd < 4; mtd++) {
                f32x4 val = Ot[mtd][nt];
                union { uint32_t u[2]; s16x4 s4; } pk;
                pk.u[0] = pk2bf(val[0] * inv, val[1] * inv);
                pk.u[1] = pk2bf(val[2] * inv, val[3] * inv);
                *(s16x4*)&attno[ob + mtd * 16 + quad * 4] = pk.s4;
            }
        }
        return;
    }

    // ---- write unnormalized partials (combined by attn_reduce) ----
    const int slot = (b * HH + h) * NENT + e;
    #pragma unroll
    for (int nt = 0; nt < 2; nt++) {
        const int i_rel = w * 32 + nt * 16 + l16;
        if (quad == 0) lpart[(size_t)slot * 128 + i_rel] = Lacc[nt][0];
        #pragma unroll
        for (int mtd = 0; mtd < 4; mtd++)
            *(s16x4*)&OpartB[(size_t)slot * 8192 + i_rel * 64 + mtd * 16 + quad * 4] =
                pack_bf16x4(Ot[mtd][nt]);
    }
}

// ---------------------------------------------------------------------------
// Combine partials for qt >= 4 (multi-chunk q-tiles only).
// ---------------------------------------------------------------------------
__global__ __launch_bounds__(256) void attn_reduce(
    const short* __restrict__ OpartB, const float* __restrict__ lpart,
    short* __restrict__ attno) {
    const int qt = 4 + blockIdx.x, h = blockIdx.y, b = blockIdx.z;
    const int t = threadIdx.x;
    const int nch = (qt >> 2) + 1;
    const int slot0 = (b * HH + h) * NENT + EBASE[qt];
    const int i0 = qt * 128;
    #pragma unroll
    for (int it = 0; it < 8; it++) {
        const int g = t + it * 256;           // 0..2047
        const int i = g >> 4, d4 = (g & 15) * 4;
        f32x4 acc = (f32x4){0.f, 0.f, 0.f, 0.f};
        float l = 0.f;
        for (int c = 0; c < nch; c++) {
            s16x4 pv = *(const s16x4*)&OpartB[(size_t)(slot0 + c) * 8192 + i * 64 + d4];
            acc[0] += bf2f(pv[0]);
            acc[1] += bf2f(pv[1]);
            acc[2] += bf2f(pv[2]);
            acc[3] += bf2f(pv[3]);
            l += lpart[(size_t)(slot0 + c) * 128 + i];
        }
        const float inv = 1.0f / l;
        union { uint32_t u[2]; s16x4 s; } pk;
        pk.u[0] = pk2bf(acc[0] * inv, acc[1] * inv);
        pk.u[1] = pk2bf(acc[2] * inv, acc[3] * inv);
        *(s16x4*)&attno[((size_t)(b * SS + i0 + i)) * HD + h * DD + d4] = pk.s;
    }
}

// ---------------------------------------------------------------------------
// Launch
// ---------------------------------------------------------------------------
extern "C" void kernel_launch(void* const* d_in, const int* in_sizes, int n_in,
                              void* d_out, int out_size, void* d_ws, size_t ws_size,
                              hipStream_t stream) {
    const float* x    = (const float*)d_in[0];
    const float* ln_g = (const float*)d_in[1];
    const float* ln_b = (const float*)d_in[2];
    const float* wq   = (const float*)d_in[3];
    const float* bq   = (const float*)d_in[4];
    const float* wk   = (const float*)d_in[5];
    const float* bk   = (const float*)d_in[6];
    const float* wv   = (const float*)d_in[7];
    const float* bv   = (const float*)d_in[8];
    const float* wo   = (const float*)d_in[9];
    const float* bo   = (const float*)d_in[10];
    float* out = (float*)d_out;

    const size_t buf = (size_t)NROW * HD;   // 4,194,304 elements
    short* xn    = (short*)d_ws;            // 8 MB
    short* qb    = xn + buf;                // q + k row-major: 16 MB
    short* vt    = qb + 2 * buf;            // V^T [1024][4096]: 8 MB
    short* attno = vt + buf;                // 8 MB
    short* wt    = attno + buf;             // 4 x 2 MB bf16 weights
    short* OpB   = wt + 4 * WELEM;          // 1280 x 8192 bf16 = 20 MB
    float* lpart = (float*)(OpB + (size_t)BB * HH * NENT * 8192);  // 0.66 MB

    prep_kernel<<<2 * NROW, 256, 0, stream>>>(x, ln_g, ln_b, xn,
                                              wq, wk, wv, wo, wt);

    // fused QKV: z=0 -> q (row-major), z=1 -> k (row-major), z=2 -> vt (transposed)
    mfma_gemm<false><<<dim3(32, 16, 3), 256, 0, stream>>>(
        xn, wt, bq, bk, bv, qb, vt, nullptr, nullptr);

    attn_split<<<dim3(NENT, HH, BB), 256, 0, stream>>>(
        qb, qb + buf, vt, OpB, lpart, attno);
    attn_reduce<<<dim3(12, HH, BB), 256, 0, stream>>>(OpB, lpart, attno);

    mfma_gemm<true><<<dim3(32, 16, 1), 256, 0, stream>>>(
        attno, wt + 3 * WELEM, bo, bo, bo, nullptr, nullptr, x, out);
}

// Round 12
// 199.793 us; speedup vs baseline: 1.8632x; 1.0135x over previous
//
#include <hip/hip_runtime.h>
#include <math.h>
#include <stdint.h>

typedef short short8 __attribute__((ext_vector_type(8)));
typedef short s16x4 __attribute__((ext_vector_type(4)));
typedef float f32x4 __attribute__((ext_vector_type(4)));

constexpr int BB = 2, SS = 2048, EE = 1024, HH = 16, DD = 64, HD = 1024;
constexpr int NROW = BB * SS;  // 4096
constexpr size_t WELEM = (size_t)1024 * 1024;  // elements per weight matrix
constexpr float LN_EPS = 1e-5f;

// split-j schedule: 40 entries per (b,h); entry e covers q-tile ENT_QT[e],
// j-tiles [ENT_C0[e]*8, min(+8, 2*qt+2)). EBASE[qt] = first entry of qt.
__device__ const int ENT_QT[40] = {0,1,2,3, 4,4, 5,5, 6,6, 7,7,
                                   8,8,8, 9,9,9, 10,10,10, 11,11,11,
                                   12,12,12,12, 13,13,13,13, 14,14,14,14, 15,15,15,15};
__device__ const int ENT_C0[40] = {0,0,0,0, 0,1, 0,1, 0,1, 0,1,
                                   0,1,2, 0,1,2, 0,1,2, 0,1,2,
                                   0,1,2,3, 0,1,2,3, 0,1,2,3, 0,1,2,3};
__device__ const int EBASE[16]  = {0,1,2,3,4,6,8,10,12,15,18,21,24,28,32,36};
constexpr int NENT = 40;

#if defined(__has_builtin)
#if __has_builtin(__builtin_amdgcn_exp2f)
#define EXP2F(x) __builtin_amdgcn_exp2f(x)
#endif
#endif
#ifndef EXP2F
#define EXP2F(x) exp2f(x)
#endif

__device__ inline short f2bf(float f) {
    union { float f; uint32_t u; } v; v.f = f;
    uint32_t r = (v.u + 0x7fffu + ((v.u >> 16) & 1u)) >> 16;
    return (short)(uint16_t)r;
}

__device__ inline float bf2f(short s) {
    return __uint_as_float(((uint32_t)(uint16_t)s) << 16);
}

// pack two f32 -> two bf16 (round-half-up) in one dword via v_perm
__device__ inline uint32_t pk2bf(float f0, float f1) {
    uint32_t u0 = __float_as_uint(f0) + 0x8000u;
    uint32_t u1 = __float_as_uint(f1) + 0x8000u;
    return __builtin_amdgcn_perm(u1, u0, 0x07060302u);
}

// truncating pack (no round-add): bias cancels between O-numerator and l-sum
__device__ inline uint32_t pk2bf_t(float f0, float f1) {
    return __builtin_amdgcn_perm(__float_as_uint(f1), __float_as_uint(f0), 0x07060302u);
}

__device__ inline s16x4 pack_bf16x4(f32x4 v) {
    union { uint32_t u[2]; s16x4 s; } r;
    r.u[0] = pk2bf(v[0], v[1]);
    r.u[1] = pk2bf(v[2], v[3]);
    return r.s;
}

#define GLOBAL_TO_LDS16(g, l) \
    __builtin_amdgcn_global_load_lds( \
        (const __attribute__((address_space(1))) void*)(g), \
        (__attribute__((address_space(3))) void*)(l), 16, 0, 0)

// ---------------------------------------------------------------------------
// Merged prep: blocks [0,4096) LayerNorm rows; [4096,8192) weight transpose.
// ---------------------------------------------------------------------------
__global__ void prep_kernel(const float* __restrict__ x,
                            const float* __restrict__ g,
                            const float* __restrict__ b,
                            short* __restrict__ xn,
                            const float* __restrict__ w0, const float* __restrict__ w1,
                            const float* __restrict__ w2, const float* __restrict__ w3,
                            short* __restrict__ wdst) {
    const int bx = blockIdx.x;
    const int t = threadIdx.x;
    if (bx < NROW) {  // ---- LayerNorm ----
        const int row = bx;
        const float* xr = x + (size_t)row * EE;
        short* onr = xn + (size_t)row * EE;
        float4 v = ((const float4*)xr)[t];
        float s  = v.x + v.y + v.z + v.w;
        float ss = v.x * v.x + v.y * v.y + v.z * v.z + v.w * v.w;
        #pragma unroll
        for (int o = 32; o > 0; o >>= 1) {
            s  += __shfl_down(s, o);
            ss += __shfl_down(ss, o);
        }
        __shared__ float sm[4], sm2[4];
        const int wid = t >> 6, lane = t & 63;
        if (lane == 0) { sm[wid] = s; sm2[wid] = ss; }
        __syncthreads();
        float ts  = sm[0] + sm[1] + sm[2] + sm[3];
        float tss = sm2[0] + sm2[1] + sm2[2] + sm2[3];
        float mean = ts * (1.0f / EE);
        float var  = tss * (1.0f / EE) - mean * mean;
        float inv  = rsqrtf(var + LN_EPS);
        float4 gv = ((const float4*)g)[t];
        float4 bv = ((const float4*)b)[t];
        s16x4 st;
        st.x = f2bf((v.x - mean) * inv * gv.x + bv.x);
        st.y = f2bf((v.y - mean) * inv * gv.y + bv.y);
        st.z = f2bf((v.z - mean) * inv * gv.z + bv.z);
        st.w = f2bf((v.w - mean) * inv * gv.w + bv.w);
        ((s16x4*)onr)[t] = st;
    } else {          // ---- weight transpose+convert ----
        const int widx = bx - NROW;          // 0..4095
        const int z = widx >> 10;
        const int rem = widx & 1023;
        const int k0 = (rem >> 5) * 32, p0 = (rem & 31) * 32;
        const float* src = (z == 0) ? w0 : (z == 1) ? w1 : (z == 2) ? w2 : w3;
        short* d = wdst + (size_t)z * WELEM;
        __shared__ float tile[32][33];
        const int tx = t & 31, ty = t >> 5;
        #pragma unroll
        for (int r = ty; r < 32; r += 8)
            tile[r][tx] = src[(size_t)(k0 + r) * 1024 + p0 + tx];
        __syncthreads();
        #pragma unroll
        for (int r = ty; r < 32; r += 8)
            d[(size_t)(p0 + r) * 1024 + k0 + tx] = f2bf(tile[tx][r]);
    }
}

// ---------------------------------------------------------------------------
// MFMA GEMM v3: 128(M)x64(N) tile, BK=64, 4 waves (each 32x64), XOR-swizzled
// global_load_lds staging, DOUBLE-BUFFERED K-loop (prefetch next chunk before
// computing current; one barrier per iter) -- attn_split's proven pattern.
// LDS 48 KB -> 3 blocks/CU. Grid: (M/128, N/64, z).
// z==2 (V projection) stores TRANSPOSED: outV[col][row] (vt [1024][4096]).
// ---------------------------------------------------------------------------
template <bool F32OUT>
__global__ __launch_bounds__(256, 3) void mfma_gemm(
    const short* __restrict__ A,
    const short* __restrict__ BtBase,
    const float* __restrict__ b0, const float* __restrict__ b1,
    const float* __restrict__ b2,
    short* __restrict__ outB, short* __restrict__ outV,
    const float* __restrict__ resid, float* __restrict__ outF) {
    constexpr int K = 1024, N = 1024;
    const int t = threadIdx.x, lane = t & 63, w = t >> 6;
    const int quad = lane >> 4, l16 = lane & 15;
    const int row0 = blockIdx.x * 128, col0 = blockIdx.y * 64;
    const int z = blockIdx.z;
    const short* Bt = BtBase + (size_t)z * WELEM;
    const float* bias = (z == 0) ? b0 : (z == 1) ? b1 : b2;

    __shared__ short As[2 * 128 * 64];   // 32 KB
    __shared__ short Bs[2 * 64 * 64];    // 16 KB

    f32x4 acc[2][4];
    #pragma unroll
    for (int i = 0; i < 2; i++)
        #pragma unroll
        for (int j = 0; j < 4; j++) acc[i][j] = (f32x4){0.f, 0.f, 0.f, 0.f};

    // staging sources: thread t covers chunk-ids {t, t+256, t+512, t+768} of A
    // (row = cid>>3, chunk c = cid&7) and {t, t+256} of B. Source k-offset is
    // XOR-swizzled so LDS slot cs of row r holds global chunk cs^(r&7).
    const int sr = t >> 3, sc = t & 7;
    const int swc = (sc ^ (sr & 7)) * 8;   // sr&7 invariant under +32
    const short* ap0 = A + (size_t)(row0 + sr) * K + swc;
    const short* ap1 = ap0 + (size_t)32 * K;
    const short* ap2 = ap0 + (size_t)64 * K;
    const short* ap3 = ap0 + (size_t)96 * K;
    const short* bp0 = Bt + (size_t)(col0 + sr) * K + swc;
    const short* bp1 = bp0 + (size_t)32 * K;

    // stage first chunk into buf 0
    GLOBAL_TO_LDS16(ap0, As + t * 8);
    GLOBAL_TO_LDS16(ap1, As + (t + 256) * 8);
    GLOBAL_TO_LDS16(ap2, As + (t + 512) * 8);
    GLOBAL_TO_LDS16(ap3, As + (t + 768) * 8);
    GLOBAL_TO_LDS16(bp0, Bs + t * 8);
    GLOBAL_TO_LDS16(bp1, Bs + (t + 256) * 8);
    __syncthreads();

    int buf = 0;
    for (int k0 = 0; k0 < K; k0 += 64) {
        if (k0 + 64 < K) {   // prefetch next chunk into other buffer
            const int oa = (buf ^ 1) * 8192;
            const int ob = (buf ^ 1) * 4096;
            GLOBAL_TO_LDS16(ap0 + k0 + 64, As + oa + t * 8);
            GLOBAL_TO_LDS16(ap1 + k0 + 64, As + oa + (t + 256) * 8);
            GLOBAL_TO_LDS16(ap2 + k0 + 64, As + oa + (t + 512) * 8);
            GLOBAL_TO_LDS16(ap3 + k0 + 64, As + oa + (t + 768) * 8);
            GLOBAL_TO_LDS16(bp0 + k0 + 64, Bs + ob + t * 8);
            GLOBAL_TO_LDS16(bp1 + k0 + 64, Bs + ob + (t + 256) * 8);
        }
        const short* Ac = As + buf * 8192;
        const short* Bc = Bs + buf * 4096;
        #pragma unroll
        for (int ks = 0; ks < 2; ks++) {
            const int ca = ((ks * 4 + quad) ^ (l16 & 7)) * 8;  // swizzled slot
            short8 af[2], bf[4];
            #pragma unroll
            for (int mt = 0; mt < 2; mt++)
                af[mt] = *(const short8*)&Ac[(w * 32 + mt * 16 + l16) * 64 + ca];
            #pragma unroll
            for (int nt = 0; nt < 4; nt++)
                bf[nt] = *(const short8*)&Bc[(nt * 16 + l16) * 64 + ca];
            #pragma unroll
            for (int mt = 0; mt < 2; mt++)
                #pragma unroll
                for (int nt = 0; nt < 4; nt++)
                    acc[mt][nt] = __builtin_amdgcn_mfma_f32_16x16x32_bf16(
                        af[mt], bf[nt], acc[mt][nt], 0, 0, 0);
        }
        __syncthreads();
        buf ^= 1;
    }

    #pragma unroll
    for (int mt = 0; mt < 2; mt++) {
        #pragma unroll
        for (int nt = 0; nt < 4; nt++) {
            const int rbase = row0 + w * 32 + mt * 16 + quad * 4;
            const int col = col0 + nt * 16 + l16;
            const float bcol = bias[col];
            if (F32OUT) {
                #pragma unroll
                for (int r = 0; r < 4; r++)
                    outF[(size_t)(rbase + r) * N + col] =
                        acc[mt][nt][r] + bcol +
                        resid[(size_t)(rbase + r) * N + col];
            } else if (z == 2) {
                union { uint32_t u[2]; s16x4 s; } pk;
                pk.u[0] = pk2bf(acc[mt][nt][0] + bcol, acc[mt][nt][1] + bcol);
                pk.u[1] = pk2bf(acc[mt][nt][2] + bcol, acc[mt][nt][3] + bcol);
                *(s16x4*)&outV[(size_t)col * NROW + rbase] = pk.s;
            } else {
                #pragma unroll
                for (int r = 0; r < 4; r++)
                    outB[(size_t)z * NROW * N + (size_t)(rbase + r) * N + col] =
                        f2bf(acc[mt][nt][r] + bcol);
            }
        }
    }
}

// ---------------------------------------------------------------------------
// Split-j MFMA flash attention (unchanged from round 10/11 passing version).
// ---------------------------------------------------------------------------
#define ATTN_ITER(JT, DIAG)                                                     \
    {                                                                           \
        const int jt_ = (JT);                                                   \
        if (jt_ + 1 < jt1) {                                                    \
            const size_t ko = (size_t)(jt_ + 1) * 64 * HD;                      \
            const int vo = (jt_ + 1) * 64;                                      \
            const int ob = (buf ^ 1) * 4096;                                    \
            GLOBAL_TO_LDS16(kb0 + ko, Kb + ob + t * 8);                         \
            GLOBAL_TO_LDS16(kb1 + ko, Kb + ob + (t + 256) * 8);                 \
            GLOBAL_TO_LDS16(vb0 + vo, Vb + ob + t * 8);                         \
            GLOBAL_TO_LDS16(vb1 + vo, Vb + ob + (t + 256) * 8);                 \
        }                                                                       \
        const short* Kc = Kb + buf * 4096;                                      \
        const short* Vc = Vb + buf * 4096;                                      \
        f32x4 s[4][2];                                                          \
        _Pragma("unroll")                                                       \
        for (int mj = 0; mj < 4; mj++)                                          \
            _Pragma("unroll")                                                   \
            for (int nt = 0; nt < 2; nt++) s[mj][nt] = (f32x4){0.f,0.f,0.f,0.f};\
        _Pragma("unroll")                                                       \
        for (int ks = 0; ks < 2; ks++) {                                        \
            const int cq = ((ks * 4 + quad) ^ sw) * 8;                          \
            short8 kf[4];                                                       \
            _Pragma("unroll")                                                   \
            for (int mj = 0; mj < 4; mj++)                                      \
                kf[mj] = *(const short8*)&Kc[(mj * 16 + l16) * 64 + cq];        \
            _Pragma("unroll")                                                   \
            for (int mj = 0; mj < 4; mj++)                                      \
                _Pragma("unroll")                                               \
                for (int nt = 0; nt < 2; nt++)                                  \
                    s[mj][nt] = __builtin_amdgcn_mfma_f32_16x16x32_bf16(        \
                        kf[mj], qreg[nt][ks], s[mj][nt], 0, 0, 0);              \
        }                                                                       \
        const int joff = (jt_ - 2 * qt) * 64;                                   \
        _Pragma("unroll")                                                       \
        for (int mj = 0; mj < 4; mj++) {                                        \
            _Pragma("unroll")                                                   \
            for (int nt = 0; nt < 2; nt++) {                                    \
                const int ir = irel + nt * 16;                                  \
                _Pragma("unroll")                                               \
                for (int r = 0; r < 4; r++) {                                   \
                    float p = EXP2F(s[mj][nt][r] * 0.18033688f);                \
                    if (DIAG) {                                                 \
                        const int jrel = joff + mj * 16 + quad * 4 + r;         \
                        if (jrel > ir) p = 0.f;                                 \
                    }                                                           \
                    s[mj][nt][r] = p;                                           \
                }                                                               \
            }                                                                   \
        }                                                                       \
        _Pragma("unroll")                                                       \
        for (int ks2 = 0; ks2 < 4; ks2++) {                                     \
            s16x4 pf[2];                                                        \
            _Pragma("unroll")                                                   \
            for (int nt = 0; nt < 2; nt++) {                                    \
                union { uint32_t u[2]; s16x4 s4; } r_;                          \
                r_.u[0] = pk2bf_t(s[ks2][nt][0], s[ks2][nt][1]);                \
                r_.u[1] = pk2bf_t(s[ks2][nt][2], s[ks2][nt][3]);                \
                pf[nt] = r_.s4;                                                 \
                Lacc[nt] = __builtin_amdgcn_mfma_f32_16x16x16bf16_1k(           \
                    onesf, pf[nt], Lacc[nt], 0, 0, 0);                          \
            }                                                                   \
            _Pragma("unroll")                                                   \
            for (int mtd = 0; mtd < 4; mtd++) {                                 \
                const int cv = (((ks2 * 2 + (quad >> 1)) ^ sw) * 8) + (quad & 1) * 4;\
                s16x4 vf = *(const s16x4*)&Vc[(mtd * 16 + l16) * 64 + cv];      \
                _Pragma("unroll")                                               \
                for (int nt = 0; nt < 2; nt++)                                  \
                    Ot[mtd][nt] = __builtin_amdgcn_mfma_f32_16x16x16bf16_1k(    \
                        vf, pf[nt], Ot[mtd][nt], 0, 0, 0);                      \
            }                                                                   \
        }                                                                       \
        __syncthreads();                                                        \
        buf ^= 1;                                                               \
    }

__global__ __launch_bounds__(256, 4) void attn_split(
    const short* __restrict__ q, const short* __restrict__ kkk,
    const short* __restrict__ vtp,
    short* __restrict__ OpartB, float* __restrict__ lpart,
    short* __restrict__ attno) {
    const int e = NENT - 1 - (int)blockIdx.x;  // heavy entries dispatch first
    const int h = blockIdx.y, b = blockIdx.z;
    const int qt = ENT_QT[e], c0 = ENT_C0[e];
    const int t = threadIdx.x, lane = t & 63, w = t >> 6;
    const int quad = lane >> 4, l16 = lane & 15;
    const int sw = l16 & 7;
    const int i0 = qt * 128;

    __shared__ short Kb[2 * 64 * 64];
    __shared__ short Vb[2 * 64 * 64];

    // ---- Q fragments -> registers (one-time global read) ----
    short8 qreg[2][2];   // [nt][ks]: row = w*32+nt*16+l16, d = ks*32+quad*8
    const size_t qoff = ((size_t)(b * SS + i0)) * HD + h * DD;
    const short* qrow = q + qoff + (size_t)(w * 32 + l16) * HD + quad * 8;
    #pragma unroll
    for (int nt = 0; nt < 2; nt++)
        #pragma unroll
        for (int ks = 0; ks < 2; ks++)
            qreg[nt][ks] = *(const short8*)(qrow + nt * 16 * HD + ks * 32);

    // ---- per-thread K/V staging sources ----
    const int r0 = t >> 3,         cs0 = t & 7;
    const int r1 = (t + 256) >> 3, cs1 = (t + 256) & 7;
    const short* kb0 = kkk + ((size_t)b * SS) * HD + h * DD + (size_t)r0 * HD + (cs0 ^ (r0 & 7)) * 8;
    const short* kb1 = kkk + ((size_t)b * SS) * HD + h * DD + (size_t)r1 * HD + (cs1 ^ (r1 & 7)) * 8;
    const short* vb0 = vtp + ((size_t)(h * 64 + r0)) * NROW + b * SS + (cs0 ^ (r0 & 7)) * 8;
    const short* vb1 = vtp + ((size_t)(h * 64 + r1)) * NROW + b * SS + (cs1 ^ (r1 & 7)) * 8;

    f32x4 Ot[4][2];        // O^T accumulators: [d-tile][i-tile]
    f32x4 Lacc[2];         // ones-MFMA row sums; per-lane reg 0 = sum for i
    #pragma unroll
    for (int mtd = 0; mtd < 4; mtd++)
        #pragma unroll
        for (int nt = 0; nt < 2; nt++) Ot[mtd][nt] = (f32x4){0.f, 0.f, 0.f, 0.f};
    Lacc[0] = (f32x4){0.f, 0.f, 0.f, 0.f};
    Lacc[1] = (f32x4){0.f, 0.f, 0.f, 0.f};
    s16x4 onesf;
    onesf[0] = onesf[1] = onesf[2] = onesf[3] = (short)0x3F80;  // bf16 1.0

    const int jt0 = c0 * 8;
    const int jt1 = min(jt0 + 8, 2 * qt + 2);
    const int irel = w * 32 + l16;

    // stage first K/V tile into buf 0
    {
        const size_t ko = (size_t)jt0 * 64 * HD;
        const int vo = jt0 * 64;
        GLOBAL_TO_LDS16(kb0 + ko, Kb + t * 8);
        GLOBAL_TO_LDS16(kb1 + ko, Kb + (t + 256) * 8);
        GLOBAL_TO_LDS16(vb0 + vo, Vb + t * 8);
        GLOBAL_TO_LDS16(vb1 + vo, Vb + (t + 256) * 8);
    }
    __syncthreads();

    int buf = 0;
    const int dmid   = min(jt1, 2 * qt);   // end of no-mask phase
    const int dstart = max(jt0, 2 * qt);   // start of masked phase
    for (int jt = jt0; jt < dmid; ++jt) ATTN_ITER(jt, false)
    for (int jt = dstart; jt < jt1; ++jt) ATTN_ITER(jt, true)

    if (qt < 4) {
        // single chunk: normalize and write attention output directly
        #pragma unroll
        for (int nt = 0; nt < 2; nt++) {
            const float inv = 1.0f / Lacc[nt][0];
            const int i_abs = i0 + w * 32 + nt * 16 + l16;
            const size_t ob = ((size_t)(b * SS + i_abs)) * HD + h * DD;
            #pragma unroll
            for (int mtd = 0; mtd < 4; mtd++) {
                f32x4 val = Ot[mtd][nt];
                union { uint32_t u[2]; s16x4 s4; } pk;
                pk.u[0] = pk2bf(val[0] * inv, val[1] * inv);
                pk.u[1] = pk2bf(val[2] * inv, val[3] * inv);
                *(s16x4*)&attno[ob + mtd * 16 + quad * 4] = pk.s4;
            }
        }
        return;
    }

    // ---- write unnormalized partials (combined by attn_reduce) ----
    const int slot = (b * HH + h) * NENT + e;
    #pragma unroll
    for (int nt = 0; nt < 2; nt++) {
        const int i_rel = w * 32 + nt * 16 + l16;
        if (quad == 0) lpart[(size_t)slot * 128 + i_rel] = Lacc[nt][0];
        #pragma unroll
        for (int mtd = 0; mtd < 4; mtd++)
            *(s16x4*)&OpartB[(size_t)slot * 8192 + i_rel * 64 + mtd * 16 + quad * 4] =
                pack_bf16x4(Ot[mtd][nt]);
    }
}

// ---------------------------------------------------------------------------
// Combine partials for qt >= 4 (multi-chunk q-tiles only).
// ---------------------------------------------------------------------------
__global__ __launch_bounds__(256) void attn_reduce(
    const short* __restrict__ OpartB, const float* __restrict__ lpart,
    short* __restrict__ attno) {
    const int qt = 4 + blockIdx.x, h = blockIdx.y, b = blockIdx.z;
    const int t = threadIdx.x;
    const int nch = (qt >> 2) + 1;
    const int slot0 = (b * HH + h) * NENT + EBASE[qt];
    const int i0 = qt * 128;
    #pragma unroll
    for (int it = 0; it < 8; it++) {
        const int g = t + it * 256;           // 0..2047
        const int i = g >> 4, d4 = (g & 15) * 4;
        f32x4 acc = (f32x4){0.f, 0.f, 0.f, 0.f};
        float l = 0.f;
        for (int c = 0; c < nch; c++) {
            s16x4 pv = *(const s16x4*)&OpartB[(size_t)(slot0 + c) * 8192 + i * 64 + d4];
            acc[0] += bf2f(pv[0]);
            acc[1] += bf2f(pv[1]);
            acc[2] += bf2f(pv[2]);
            acc[3] += bf2f(pv[3]);
            l += lpart[(size_t)(slot0 + c) * 128 + i];
        }
        const float inv = 1.0f / l;
        union { uint32_t u[2]; s16x4 s; } pk;
        pk.u[0] = pk2bf(acc[0] * inv, acc[1] * inv);
        pk.u[1] = pk2bf(acc[2] * inv, acc[3] * inv);
        *(s16x4*)&attno[((size_t)(b * SS + i0 + i)) * HD + h * DD + d4] = pk.s;
    }
}

// ---------------------------------------------------------------------------
// Launch
// ---------------------------------------------------------------------------
extern "C" void kernel_launch(void* const* d_in, const int* in_sizes, int n_in,
                              void* d_out, int out_size, void* d_ws, size_t ws_size,
                              hipStream_t stream) {
    const float* x    = (const float*)d_in[0];
    const float* ln_g = (const float*)d_in[1];
    const float* ln_b = (const float*)d_in[2];
    const float* wq   = (const float*)d_in[3];
    const float* bq   = (const float*)d_in[4];
    const float* wk   = (const float*)d_in[5];
    const float* bk   = (const float*)d_in[6];
    const float* wv   = (const float*)d_in[7];
    const float* bv   = (const float*)d_in[8];
    const float* wo   = (const float*)d_in[9];
    const float* bo   = (const float*)d_in[10];
    float* out = (float*)d_out;

    const size_t buf = (size_t)NROW * HD;   // 4,194,304 elements
    short* xn    = (short*)d_ws;            // 8 MB
    short* qb    = xn + buf;                // q + k row-major: 16 MB
    short* vt    = qb + 2 * buf;            // V^T [1024][4096]: 8 MB
    short* attno = vt + buf;                // 8 MB
    short* wt    = attno + buf;             // 4 x 2 MB bf16 weights
    short* OpB   = wt + 4 * WELEM;          // 1280 x 8192 bf16 = 20 MB
    float* lpart = (float*)(OpB + (size_t)BB * HH * NENT * 8192);  // 0.66 MB

    prep_kernel<<<2 * NROW, 256, 0, stream>>>(x, ln_g, ln_b, xn,
                                              wq, wk, wv, wo, wt);

    // fused QKV: z=0 -> q (row-major), z=1 -> k (row-major), z=2 -> vt (transposed)
    mfma_gemm<false><<<dim3(32, 16, 3), 256, 0, stream>>>(
        xn, wt, bq, bk, bv, qb, vt, nullptr, nullptr);

    attn_split<<<dim3(NENT, HH, BB), 256, 0, stream>>>(
        qb, qb + buf, vt, OpB, lpart, attno);
    attn_reduce<<<dim3(12, HH, BB), 256, 0, stream>>>(OpB, lpart, attno);

    mfma_gemm<true><<<dim3(32, 16, 1), 256, 0, stream>>>(
        attno, wt + 3 * WELEM, bo, bo, bo, nullptr, nullptr, x, out);
}